// Round 2
// baseline (39888.928 us; speedup 1.0000x reference)
//
#include <hip/hip_runtime.h>

// DARTS RNN cell, fp32. B=128, T=256, HID=512, EMB=300, IN=360.
// Design notes (round 1, resubmitted after infra timeout):
//  - Encoder folded into step-GEMM: Wcat[872][1024] = [W_enc@W0[:300]; W0[300:]],
//    bias b0[1024] = b_enc@W0[:300]. Built once per call in d_ws.
//  - Per timestep: 5 launches following the dependency DAG:
//      A: s0 = f([x_t,h] @ Wcat)            (tanh)
//      B: s1=f(s0,W1,tanh), s4=f(s0,W4,relu)
//      C: s2=f(s1,W2,relu), s3=f(s1,W3,tanh), s7=f(s4,W7,tanh)
//      D: s5=f(s2,W5,id),   s6=f(s3,W6,sigm)
//      E: s8=f(s5,W8,relu) + merge h=mean(s1..s8), out[b][t]=h*mask
//  - Conn GEMM: block = 256 thr = 64 j-lanes x 4 row-groups, tile 8 rows x 64 j,
//    both c and g dots per thread. Acts from LDS (broadcast), weights from
//    global (coalesced 256B/wave, L1/L2-resident).

#define HIDN 512
#define EMBN 300
#define INDN 360
#define BN   128
#define TN   256
#define KCAT 872               // 360 + 512
#define WSZ  (512*1024)        // elements per Ws[i]

__device__ __forceinline__ float sigf(float x){ return 1.0f/(1.0f + __expf(-x)); }
__device__ __forceinline__ float tanh_fast(float x){ return 2.0f*sigf(2.0f*x) - 1.0f; }
__device__ __forceinline__ float actf(int a, float g){
  if (a==0) return tanh_fast(g);
  if (a==1) return fmaxf(g, 0.0f);
  if (a==2) return g;
  return sigf(g);
}

struct ConnDesc { const float* in; float* out; const float* w; int act; };
struct ConnArgs { ConnDesc d[3]; };

// ---- one-time (per call) weight prep: Wcat + b0 --------------------------
__global__ __launch_bounds__(256) void build_wcat(
    const float* __restrict__ Wenc, const float* __restrict__ benc,
    const float* __restrict__ W0, float* __restrict__ wcat, float* __restrict__ b0)
{
  int j = blockIdx.x*256 + threadIdx.x;   // 0..1023
  int k = blockIdx.y;                     // 0..872 (872 == bias row)
  if (k < INDN) {
    float acc = 0.f;
    for (int e = 0; e < EMBN; ++e) acc = fmaf(Wenc[k*EMBN + e], W0[(size_t)e*1024 + j], acc);
    wcat[(size_t)k*1024 + j] = acc;
  } else if (k < KCAT) {
    wcat[(size_t)k*1024 + j] = W0[(size_t)(k - 60)*1024 + j];  // 300 + (k-360)
  } else {
    float acc = 0.f;
    for (int e = 0; e < EMBN; ++e) acc = fmaf(benc[e], W0[(size_t)e*1024 + j], acc);
    b0[j] = acc;
  }
}

// ---- stage A: s0 from [x_t, h] @ Wcat ------------------------------------
__global__ __launch_bounds__(256) void stage_a(
    const float* __restrict__ inputs, const float* __restrict__ wcat,
    const float* __restrict__ b0, const float* __restrict__ h,
    float* __restrict__ s0, int t)
{
  __shared__ float inp[8][KCAT];
  const int tid = threadIdx.x;
  const int r0 = blockIdx.y * 8;
  for (int i = tid; i < 8*(INDN/4); i += 256) {
    int r = i / (INDN/4), c = i % (INDN/4);
    ((float4*)&inp[r][0])[c] =
      ((const float4*)(inputs + ((size_t)(r0+r)*TN + t)*INDN))[c];
  }
  for (int i = tid; i < 8*(HIDN/4); i += 256) {
    int r = i / (HIDN/4), c = i % (HIDN/4);
    ((float4*)&inp[r][INDN])[c] = ((const float4*)(h + (size_t)(r0+r)*HIDN))[c];
  }
  __syncthreads();

  const int jl = tid & 63, rg = tid >> 6;
  const int j  = blockIdx.x*64 + jl;          // 0..511
  const int ra = rg*2, rb = ra + 1;
  const float* wc = wcat + j;
  const float* wg = wcat + 512 + j;
  float c0=0.f, g0=0.f, c1=0.f, g1=0.f;
  for (int k = 0; k < KCAT; k += 4) {
    float4 a0 = *(const float4*)&inp[ra][k];
    float4 a1 = *(const float4*)&inp[rb][k];
    #pragma unroll
    for (int u = 0; u < 4; ++u) {
      float wcv = wc[(size_t)(k+u)*1024];
      float wgv = wg[(size_t)(k+u)*1024];
      float a0u = (&a0.x)[u], a1u = (&a1.x)[u];
      c0 = fmaf(a0u, wcv, c0); g0 = fmaf(a0u, wgv, g0);
      c1 = fmaf(a1u, wcv, c1); g1 = fmaf(a1u, wgv, g1);
    }
  }
  float bc = b0[j], bg = b0[512 + j];
  {
    float hv = inp[ra][INDN + j];
    s0[(size_t)(r0+ra)*HIDN + j] = hv + sigf(c0 + bc)*(tanh_fast(g0 + bg) - hv);
  }
  {
    float hv = inp[rb][INDN + j];
    s0[(size_t)(r0+rb)*HIDN + j] = hv + sigf(c1 + bc)*(tanh_fast(g1 + bg) - hv);
  }
}

// ---- generic connection GEMM: s_out = inp + sig(c)*(act(g) - inp) --------
__global__ __launch_bounds__(256) void conn_k(ConnArgs args)
{
  ConnDesc d = args.d[blockIdx.z];
  __shared__ float inp[8][HIDN];
  const int tid = threadIdx.x;
  const int r0 = blockIdx.y * 8;
  const float* src = d.in + (size_t)r0*HIDN;
  for (int i = tid; i < 8*HIDN/4; i += 256)
    ((float4*)&inp[0][0])[i] = ((const float4*)src)[i];
  __syncthreads();

  const int jl = tid & 63, rg = tid >> 6;
  const int j  = blockIdx.x*64 + jl;
  const int ra = rg*2, rb = ra + 1;
  const float* wc = d.w + j;
  const float* wg = d.w + 512 + j;
  float c0=0.f, g0=0.f, c1=0.f, g1=0.f;
  for (int k = 0; k < HIDN; k += 4) {
    float4 a0 = *(const float4*)&inp[ra][k];
    float4 a1 = *(const float4*)&inp[rb][k];
    #pragma unroll
    for (int u = 0; u < 4; ++u) {
      float wcv = wc[(size_t)(k+u)*1024];
      float wgv = wg[(size_t)(k+u)*1024];
      float a0u = (&a0.x)[u], a1u = (&a1.x)[u];
      c0 = fmaf(a0u, wcv, c0); g0 = fmaf(a0u, wgv, g0);
      c1 = fmaf(a1u, wcv, c1); g1 = fmaf(a1u, wgv, g1);
    }
  }
  const int act = d.act;
  {
    float iv = inp[ra][j];
    d.out[(size_t)(r0+ra)*HIDN + j] = iv + sigf(c0)*(actf(act, g0) - iv);
  }
  {
    float iv = inp[rb][j];
    d.out[(size_t)(r0+rb)*HIDN + j] = iv + sigf(c1)*(actf(act, g1) - iv);
  }
}

// ---- stage E: s8 (relu conn on s5) + merge + output ----------------------
__global__ __launch_bounds__(256) void stage_e(
    const float* __restrict__ s5, const float* __restrict__ w,
    const float* __restrict__ S, float* __restrict__ h,
    float* __restrict__ out, const float* __restrict__ masks, int t)
{
  __shared__ float inp[8][HIDN];
  const int tid = threadIdx.x;
  const int r0 = blockIdx.y * 8;
  const float* src = s5 + (size_t)r0*HIDN;
  for (int i = tid; i < 8*HIDN/4; i += 256)
    ((float4*)&inp[0][0])[i] = ((const float4*)src)[i];
  __syncthreads();

  const int jl = tid & 63, rg = tid >> 6;
  const int j  = blockIdx.x*64 + jl;
  const int ra = rg*2, rb = ra + 1;
  const float* wc = w + j;
  const float* wg = w + 512 + j;
  float c0=0.f, g0=0.f, c1=0.f, g1=0.f;
  for (int k = 0; k < HIDN; k += 4) {
    float4 a0 = *(const float4*)&inp[ra][k];
    float4 a1 = *(const float4*)&inp[rb][k];
    #pragma unroll
    for (int u = 0; u < 4; ++u) {
      float wcv = wc[(size_t)(k+u)*1024];
      float wgv = wg[(size_t)(k+u)*1024];
      float a0u = (&a0.x)[u], a1u = (&a1.x)[u];
      c0 = fmaf(a0u, wcv, c0); g0 = fmaf(a0u, wgv, g0);
      c1 = fmaf(a1u, wcv, c1); g1 = fmaf(a1u, wgv, g1);
    }
  }
  #pragma unroll
  for (int p = 0; p < 2; ++p) {
    int rl = (p == 0) ? ra : rb;
    float cc = (p == 0) ? c0 : c1;
    float gg = (p == 0) ? g0 : g1;
    int r = r0 + rl;
    float iv = inp[rl][j];
    float s8 = iv + sigf(cc)*(fmaxf(gg, 0.f) - iv);
    float m = s8;
    #pragma unroll
    for (int i = 1; i <= 7; ++i) m += S[(size_t)i*(BN*HIDN) + (size_t)r*HIDN + j];
    m *= 0.125f;
    h[(size_t)r*HIDN + j] = m;
    out[((size_t)r*TN + t)*HIDN + j] = m * masks[(size_t)r*TN + t];
  }
}

extern "C" void kernel_launch(void* const* d_in, const int* in_sizes, int n_in,
                              void* d_out, int out_size, void* d_ws, size_t ws_size,
                              hipStream_t stream)
{
  const float* inputs = (const float*)d_in[0];
  // d_in[1] = hidden: unused by the reference (h0 is zeros)
  const float* masks  = (const float*)d_in[2];
  const float* Wenc   = (const float*)d_in[3];
  const float* benc   = (const float*)d_in[4];
  const float* W0     = (const float*)d_in[5];
  const float* Wsp    = (const float*)d_in[6];
  float* out = (float*)d_out;
  float* ws  = (float*)d_ws;

  // ws layout (floats)
  float* wcat = ws;                         // 872*1024 = 892928
  float* b0   = ws + 892928;                // 1024
  float* h    = ws + 893952;                // 65536
  float* S    = ws + 959488;                // 9 * 65536
  auto s = [&](int i){ return S + (size_t)i*(BN*HIDN); };
  auto W = [&](int i){ return Wsp + (size_t)i*WSZ; };

  hipMemsetAsync(h, 0, (size_t)BN*HIDN*sizeof(float), stream);
  build_wcat<<<dim3(4, KCAT+1), 256, 0, stream>>>(Wenc, benc, W0, wcat, b0);

  const dim3 grid2(8, 16), blk(256);
  for (int t = 0; t < TN; ++t) {
    stage_a<<<grid2, blk, 0, stream>>>(inputs, wcat, b0, h, s(0), t);

    ConnArgs cb;  // s1 = tanh-conn(s0, W1); s4 = relu-conn(s0, W4)
    cb.d[0] = { s(0), s(1), W(0), 0 };
    cb.d[1] = { s(0), s(4), W(3), 1 };
    cb.d[2] = cb.d[0];
    conn_k<<<dim3(8,16,2), blk, 0, stream>>>(cb);

    ConnArgs cc;  // s2 = relu(s1,W2); s3 = tanh(s1,W3); s7 = tanh(s4,W7)
    cc.d[0] = { s(1), s(2), W(1), 1 };
    cc.d[1] = { s(1), s(3), W(2), 0 };
    cc.d[2] = { s(4), s(7), W(6), 0 };
    conn_k<<<dim3(8,16,3), blk, 0, stream>>>(cc);

    ConnArgs cd;  // s5 = id(s2,W5); s6 = sigm(s3,W6)
    cd.d[0] = { s(2), s(5), W(4), 2 };
    cd.d[1] = { s(3), s(6), W(5), 3 };
    cd.d[2] = cd.d[0];
    conn_k<<<dim3(8,16,2), blk, 0, stream>>>(cd);

    stage_e<<<grid2, blk, 0, stream>>>(s(5), W(7), S, h, out, masks, t);
  }
}

// Round 3
// 26755.737 us; speedup vs baseline: 1.4909x; 1.4909x over previous
//
#include <hip/hip_runtime.h>

// DARTS RNN cell, fp32. B=128, T=256, HID=512, EMB=300, IN=360.
// Round 3:
//  - 4 rows/block (was 8): 256 blocks/GEMM, stages stack 2-3 GEMMs/launch
//    -> 2-3 waves/SIMD, latency hidden by TLP.
//  - k-interleaved weight layout wT[k/4][j][4]: inner loop = 2x dwordx4
//    weight loads + 8 FMA per 4-k chunk (was 8 scalar loads). One-time
//    transform of Ws into d_ws; Wcat built interleaved directly.
//  - Explicit 1-chunk register prefetch in dot loop.
//  - template<bool VEC> fallback to plain layout if ws_size too small.

#define HIDN 512
#define EMBN 300
#define INDN 360
#define BN   128
#define TN   256
#define KCAT 872               // 360 + 512
#define WSZ  (512*1024)        // elements per Ws[i]

__device__ __forceinline__ float sigf(float x){ return 1.0f/(1.0f + __expf(-x)); }
__device__ __forceinline__ float tanh_fast(float x){ return 2.0f*sigf(2.0f*x) - 1.0f; }
__device__ __forceinline__ float actf(int a, float g){
  if (a==0) return tanh_fast(g);
  if (a==1) return fmaxf(g, 0.0f);
  if (a==2) return g;
  return sigf(g);
}

// ---- dot kernels: c,g accumulators over K, prefetched -------------------
// VEC layout: wT[kc][j][u] flat = kc*4096 + j*4 + u  (u = k%4, kc = k/4)
template<int KL4>
__device__ __forceinline__ void dot_vec(const float* __restrict__ pc,
                                        const float* __restrict__ pg,
                                        const float* __restrict__ act,
                                        float& c, float& g)
{
  float4 wc = *(const float4*)pc;
  float4 wg = *(const float4*)pg;
  float4 a  = *(const float4*)act;
  for (int kc = 1; kc < KL4; ++kc) {
    float4 nwc = *(const float4*)(pc + (size_t)kc*4096);
    float4 nwg = *(const float4*)(pg + (size_t)kc*4096);
    float4 na  = *(const float4*)(act + kc*4);
    #pragma unroll
    for (int u = 0; u < 4; ++u) {
      c = fmaf((&a.x)[u], (&wc.x)[u], c);
      g = fmaf((&a.x)[u], (&wg.x)[u], g);
    }
    wc = nwc; wg = nwg; a = na;
  }
  #pragma unroll
  for (int u = 0; u < 4; ++u) {
    c = fmaf((&a.x)[u], (&wc.x)[u], c);
    g = fmaf((&a.x)[u], (&wg.x)[u], g);
  }
}

// plain layout: w[k][j] flat = k*1024 + j
template<int KL4>
__device__ __forceinline__ void dot_plain(const float* __restrict__ w,
                                          const float* __restrict__ act,
                                          float& c, float& g)
{
  float wc[4], wg[4];
  #pragma unroll
  for (int u = 0; u < 4; ++u) { wc[u] = w[u*1024]; wg[u] = w[u*1024 + 512]; }
  float4 a = *(const float4*)act;
  for (int kc = 1; kc < KL4; ++kc) {
    float nwc[4], nwg[4];
    const float* p = w + (size_t)kc*4096;
    #pragma unroll
    for (int u = 0; u < 4; ++u) { nwc[u] = p[u*1024]; nwg[u] = p[u*1024 + 512]; }
    float4 na = *(const float4*)(act + kc*4);
    #pragma unroll
    for (int u = 0; u < 4; ++u) {
      c = fmaf((&a.x)[u], wc[u], c);
      g = fmaf((&a.x)[u], wg[u], g);
    }
    #pragma unroll
    for (int u = 0; u < 4; ++u) { wc[u] = nwc[u]; wg[u] = nwg[u]; }
    a = na;
  }
  #pragma unroll
  for (int u = 0; u < 4; ++u) {
    c = fmaf((&a.x)[u], wc[u], c);
    g = fmaf((&a.x)[u], wg[u], g);
  }
}

struct ConnDesc { const float* in; float* out; const float* w; int act; };
struct ConnArgs { ConnDesc d[3]; };

// ---- one-time weight prep ------------------------------------------------
// Transpose Ws[m][k][j] -> wsT[m][k/4][j][k%4]; both sides coalesced.
__global__ __launch_bounds__(256) void transpose_ws(
    const float* __restrict__ Wsp, float* __restrict__ wsT)
{
  int j  = blockIdx.x*256 + threadIdx.x;  // 0..1023
  int kc = blockIdx.y;                    // 0..127
  int m  = blockIdx.z;                    // 0..7
  const float* src = Wsp + (size_t)m*WSZ;
  float4 v;
  v.x = src[(size_t)(kc*4+0)*1024 + j];
  v.y = src[(size_t)(kc*4+1)*1024 + j];
  v.z = src[(size_t)(kc*4+2)*1024 + j];
  v.w = src[(size_t)(kc*4+3)*1024 + j];
  *(float4*)(wsT + (size_t)m*WSZ + (size_t)kc*4096 + (size_t)j*4) = v;
}

// Wcat = [W_enc@W0[:300]; W0[300:]] (rows 0..871), b0 = b_enc@W0[:300].
template<bool VEC>
__global__ __launch_bounds__(256) void build_wcat(
    const float* __restrict__ Wenc, const float* __restrict__ benc,
    const float* __restrict__ W0, float* __restrict__ wcat, float* __restrict__ b0)
{
  int j = blockIdx.x*256 + threadIdx.x;   // 0..1023
  int k = blockIdx.y;                     // 0..872 (872 == bias row)
  if (k < KCAT) {
    float v;
    if (k < INDN) {
      float acc = 0.f;
      for (int e = 0; e < EMBN; ++e) acc = fmaf(Wenc[k*EMBN + e], W0[(size_t)e*1024 + j], acc);
      v = acc;
    } else {
      v = W0[(size_t)(k - 60)*1024 + j];  // 300 + (k-360)
    }
    if (VEC) wcat[(size_t)(k>>2)*4096 + (size_t)j*4 + (k&3)] = v;
    else     wcat[(size_t)k*1024 + j] = v;
  } else {
    float acc = 0.f;
    for (int e = 0; e < EMBN; ++e) acc = fmaf(benc[e], W0[(size_t)e*1024 + j], acc);
    b0[j] = acc;
  }
}

// ---- stage A: s0 from [x_t, h] @ Wcat ------------------------------------
template<bool VEC>
__global__ __launch_bounds__(256) void stage_a(
    const float* __restrict__ inputs, const float* __restrict__ wcat,
    const float* __restrict__ b0, const float* __restrict__ h,
    float* __restrict__ s0, int t)
{
  __shared__ float inp[4][KCAT];
  const int tid = threadIdx.x;
  const int r0 = blockIdx.y * 4;
  for (int i = tid; i < 4*(INDN/4); i += 256) {
    int r = i / (INDN/4), c = i % (INDN/4);
    ((float4*)&inp[r][0])[c] =
      ((const float4*)(inputs + ((size_t)(r0+r)*TN + t)*INDN))[c];
  }
  for (int i = tid; i < 4*(HIDN/4); i += 256) {
    int r = i / (HIDN/4), c = i % (HIDN/4);
    ((float4*)&inp[r][INDN])[c] = ((const float4*)(h + (size_t)(r0+r)*HIDN))[c];
  }
  __syncthreads();

  const int jl = tid & 63, rg = tid >> 6;
  const int j  = blockIdx.x*64 + jl;          // 0..511
  float c = 0.f, g = 0.f;
  if (VEC) dot_vec<KCAT/4>(wcat + (size_t)j*4, wcat + (size_t)(j+512)*4, &inp[rg][0], c, g);
  else     dot_plain<KCAT/4>(wcat + j, &inp[rg][0], c, g);
  c += b0[j]; g += b0[512 + j];
  float hv = inp[rg][INDN + j];
  s0[(size_t)(r0+rg)*HIDN + j] = hv + sigf(c)*(tanh_fast(g) - hv);
}

// ---- generic connection GEMM: s_out = inp + sig(c)*(act(g) - inp) --------
template<bool VEC>
__global__ __launch_bounds__(256) void conn_k(ConnArgs args)
{
  ConnDesc d = args.d[blockIdx.z];
  __shared__ float inp[4][HIDN];
  const int tid = threadIdx.x;
  const int r0 = blockIdx.y * 4;
  const float* src = d.in + (size_t)r0*HIDN;
  for (int i = tid; i < 4*HIDN/4; i += 256)
    ((float4*)&inp[0][0])[i] = ((const float4*)src)[i];
  __syncthreads();

  const int jl = tid & 63, rg = tid >> 6;
  const int j  = blockIdx.x*64 + jl;
  float c = 0.f, g = 0.f;
  if (VEC) dot_vec<HIDN/4>(d.w + (size_t)j*4, d.w + (size_t)(j+512)*4, &inp[rg][0], c, g);
  else     dot_plain<HIDN/4>(d.w + j, &inp[rg][0], c, g);
  float iv = inp[rg][j];
  d.out[(size_t)(r0+rg)*HIDN + j] = iv + sigf(c)*(actf(d.act, g) - iv);
}

// ---- stage E: s8 (relu conn on s5) + merge + output ----------------------
template<bool VEC>
__global__ __launch_bounds__(256) void stage_e(
    const float* __restrict__ s5, const float* __restrict__ w,
    const float* __restrict__ S, float* __restrict__ h,
    float* __restrict__ out, const float* __restrict__ masks, int t)
{
  __shared__ float inp[4][HIDN];
  const int tid = threadIdx.x;
  const int r0 = blockIdx.y * 4;
  const float* src = s5 + (size_t)r0*HIDN;
  for (int i = tid; i < 4*HIDN/4; i += 256)
    ((float4*)&inp[0][0])[i] = ((const float4*)src)[i];
  __syncthreads();

  const int jl = tid & 63, rg = tid >> 6;
  const int j  = blockIdx.x*64 + jl;
  float c = 0.f, g = 0.f;
  if (VEC) dot_vec<HIDN/4>(w + (size_t)j*4, w + (size_t)(j+512)*4, &inp[rg][0], c, g);
  else     dot_plain<HIDN/4>(w + j, &inp[rg][0], c, g);

  const int r = r0 + rg;
  float iv = inp[rg][j];
  float s8 = iv + sigf(c)*(fmaxf(g, 0.f) - iv);
  float m = s8;
  #pragma unroll
  for (int i = 1; i <= 7; ++i) m += S[(size_t)i*(BN*HIDN) + (size_t)r*HIDN + j];
  m *= 0.125f;
  h[(size_t)r*HIDN + j] = m;
  out[((size_t)r*TN + t)*HIDN + j] = m * masks[(size_t)r*TN + t];
}

// ---- host-side step loop, templated on layout ----------------------------
template<bool VEC>
static void run_all(const float* inputs, const float* masks,
                    const float* Wenc, const float* benc,
                    const float* W0, const float* Wsp,
                    float* out, float* ws, hipStream_t stream)
{
  // ws layout (floats):
  float* wcat = ws;                          // 872*1024 = 892928
  float* b0   = ws + 892928;                 // 1024
  float* h    = ws + 893952;                 // 65536
  float* S    = ws + 959488;                 // 9 * 65536 = 589824
  float* wsT  = ws + 1549312;                // 8 * 524288 (VEC only)
  auto s = [&](int i){ return S + (size_t)i*(BN*HIDN); };
  auto W = [&](int i){ return (VEC ? wsT : Wsp) + (size_t)i*WSZ; };

  hipMemsetAsync(h, 0, (size_t)BN*HIDN*sizeof(float), stream);
  build_wcat<VEC><<<dim3(4, KCAT+1), 256, 0, stream>>>(Wenc, benc, W0, wcat, b0);
  if (VEC)
    transpose_ws<<<dim3(4, 128, 8), 256, 0, stream>>>(Wsp, wsT);

  const dim3 grid2(8, 32), blk(256);
  for (int t = 0; t < TN; ++t) {
    stage_a<VEC><<<grid2, blk, 0, stream>>>(inputs, wcat, b0, h, s(0), t);

    ConnArgs cb;  // s1 = tanh-conn(s0, W1); s4 = relu-conn(s0, W4)
    cb.d[0] = { s(0), s(1), W(0), 0 };
    cb.d[1] = { s(0), s(4), W(3), 1 };
    cb.d[2] = cb.d[0];
    conn_k<VEC><<<dim3(8,32,2), blk, 0, stream>>>(cb);

    ConnArgs cc;  // s2 = relu(s1,W2); s3 = tanh(s1,W3); s7 = tanh(s4,W7)
    cc.d[0] = { s(1), s(2), W(1), 1 };
    cc.d[1] = { s(1), s(3), W(2), 0 };
    cc.d[2] = { s(4), s(7), W(6), 0 };
    conn_k<VEC><<<dim3(8,32,3), blk, 0, stream>>>(cc);

    ConnArgs cd;  // s5 = id(s2,W5); s6 = sigm(s3,W6)
    cd.d[0] = { s(2), s(5), W(4), 2 };
    cd.d[1] = { s(3), s(6), W(5), 3 };
    cd.d[2] = cd.d[0];
    conn_k<VEC><<<dim3(8,32,2), blk, 0, stream>>>(cd);

    stage_e<VEC><<<grid2, blk, 0, stream>>>(s(5), W(7), S, h, out, masks, t);
  }
}

extern "C" void kernel_launch(void* const* d_in, const int* in_sizes, int n_in,
                              void* d_out, int out_size, void* d_ws, size_t ws_size,
                              hipStream_t stream)
{
  const float* inputs = (const float*)d_in[0];
  // d_in[1] = hidden: unused by the reference (h0 is zeros)
  const float* masks  = (const float*)d_in[2];
  const float* Wenc   = (const float*)d_in[3];
  const float* benc   = (const float*)d_in[4];
  const float* W0     = (const float*)d_in[5];
  const float* Wsp    = (const float*)d_in[6];
  float* out = (float*)d_out;
  float* ws  = (float*)d_ws;

  const size_t need_vec = (size_t)(1549312 + 8*WSZ) * sizeof(float);  // ~22.7 MB
  if (ws_size >= need_vec)
    run_all<true >(inputs, masks, Wenc, benc, W0, Wsp, out, ws, stream);
  else
    run_all<false>(inputs, masks, Wenc, benc, W0, Wsp, out, ws, stream);
}

// Round 4
// 24552.280 us; speedup vs baseline: 1.6247x; 1.0897x over previous
//
#include <hip/hip_runtime.h>

// DARTS RNN cell, fp32. B=128, T=256, HID=512, EMB=300, IN=360.
// Round 4:
//  - Depth-8 software-pipelined dot loop (8 rotating reg slots, static
//    indices): load window ~224 cyc covers L2 latency even at 1 wave/SIMD.
//  - Overrun prefetch lands in slack memory (never consumed by FMA).
//  - 1 row/thread, 4 rows/block: 256 blocks/GEMM -> full chip for A/E,
//    2-3 blocks/CU for stacked conn stages.
//  - grid.x = j-tile => bid%8 = j-tile => per-XCD L2 keeps its 2.5MB j-slice
//    of all weights hot across all 256 steps.
//  - k-interleaved weight layout wT[kc][jj][4] (VEC); plain fallback if ws
//    too small.

#define HIDN 512
#define EMBN 300
#define INDN 360
#define BN   128
#define TN   256
#define KCAT 872               // 360 + 512
#define WSZ  (512*1024)        // elements per Ws[i]

__device__ __forceinline__ float sigf(float x){ return 1.0f/(1.0f + __expf(-x)); }
__device__ __forceinline__ float tanh_fast(float x){ return 2.0f*sigf(2.0f*x) - 1.0f; }
__device__ __forceinline__ float actf(int a, float g){
  if (a==0) return tanh_fast(g);
  if (a==1) return fmaxf(g, 0.0f);
  if (a==2) return g;
  return sigf(g);
}
#define F4(v,u) ((&(v).x)[u])

// ---- depth-8 pipelined dot (VEC layout: w4[kc*1024 + jj], jj=j or j+512) --
// KC = number of 4-k chunks. Loads run 8 chunks ahead; overrun loads hit
// slack memory and are never FMA'd. arow reads overrun into LDS pad.
template<int KC>
__device__ __forceinline__ void dot8(const float4* __restrict__ WC,
                                     const float4* __restrict__ WG,
                                     const float*  __restrict__ arow,
                                     float& cacc, float& gacc)
{
  float4 wcb[8], wgb[8], ab[8];
  #pragma unroll
  for (int p = 0; p < 8; ++p) {
    wcb[p] = WC[(size_t)p*1024];
    wgb[p] = WG[(size_t)p*1024];
    ab[p]  = *(const float4*)(arow + p*4);
  }
  float c = 0.f, g = 0.f;
  constexpr int MAIN = (KC/8)*8;
  for (int kc = 0; kc < MAIN; kc += 8) {
    #pragma unroll
    for (int p = 0; p < 8; ++p) {
      float4 w1 = wcb[p], w2 = wgb[p], a = ab[p];
      const size_t kn = (size_t)(kc + 8 + p);
      wcb[p] = WC[kn*1024];
      wgb[p] = WG[kn*1024];
      ab[p]  = *(const float4*)(arow + kn*4);
      #pragma unroll
      for (int u = 0; u < 4; ++u) {
        c = fmaf(F4(a,u), F4(w1,u), c);
        g = fmaf(F4(a,u), F4(w2,u), g);
      }
    }
  }
  #pragma unroll
  for (int p = 0; p < KC - MAIN; ++p) {
    float4 w1 = wcb[p], w2 = wgb[p], a = ab[p];
    #pragma unroll
    for (int u = 0; u < 4; ++u) {
      c = fmaf(F4(a,u), F4(w1,u), c);
      g = fmaf(F4(a,u), F4(w2,u), g);
    }
  }
  cacc = c; gacc = g;
}

// plain layout fallback: w[k*1024 + j], depth-1 prefetch
template<int KL4>
__device__ __forceinline__ void dot_plain(const float* __restrict__ w,
                                          const float* __restrict__ act,
                                          float& cacc, float& gacc)
{
  float wc[4], wg[4];
  #pragma unroll
  for (int u = 0; u < 4; ++u) { wc[u] = w[u*1024]; wg[u] = w[u*1024 + 512]; }
  float4 a = *(const float4*)act;
  float c = 0.f, g = 0.f;
  for (int kc = 1; kc < KL4; ++kc) {
    float nwc[4], nwg[4];
    const float* p = w + (size_t)kc*4096;
    #pragma unroll
    for (int u = 0; u < 4; ++u) { nwc[u] = p[u*1024]; nwg[u] = p[u*1024 + 512]; }
    float4 na = *(const float4*)(act + kc*4);
    #pragma unroll
    for (int u = 0; u < 4; ++u) {
      c = fmaf(F4(a,u), wc[u], c);
      g = fmaf(F4(a,u), wg[u], g);
    }
    #pragma unroll
    for (int u = 0; u < 4; ++u) { wc[u] = nwc[u]; wg[u] = nwg[u]; }
    a = na;
  }
  #pragma unroll
  for (int u = 0; u < 4; ++u) {
    c = fmaf(F4(a,u), wc[u], c);
    g = fmaf(F4(a,u), wg[u], g);
  }
  cacc = c; gacc = g;
}

struct ConnDesc { const float* in; float* out; const float* w; int act; };
struct ConnArgs { ConnDesc d[3]; };

// ---- one-time weight prep ------------------------------------------------
__global__ __launch_bounds__(256) void transpose_ws(
    const float* __restrict__ Wsp, float* __restrict__ wsT)
{
  int j  = blockIdx.x*256 + threadIdx.x;  // 0..1023
  int kc = blockIdx.y;                    // 0..127
  int m  = blockIdx.z;                    // 0..7
  const float* src = Wsp + (size_t)m*WSZ;
  float4 v;
  v.x = src[(size_t)(kc*4+0)*1024 + j];
  v.y = src[(size_t)(kc*4+1)*1024 + j];
  v.z = src[(size_t)(kc*4+2)*1024 + j];
  v.w = src[(size_t)(kc*4+3)*1024 + j];
  *(float4*)(wsT + (size_t)m*WSZ + (size_t)kc*4096 + (size_t)j*4) = v;
}

template<bool VEC>
__global__ __launch_bounds__(256) void build_wcat(
    const float* __restrict__ Wenc, const float* __restrict__ benc,
    const float* __restrict__ W0, float* __restrict__ wcat, float* __restrict__ b0)
{
  int j = blockIdx.x*256 + threadIdx.x;   // 0..1023
  int k = blockIdx.y;                     // 0..872 (872 == bias row)
  if (k < KCAT) {
    float v;
    if (k < INDN) {
      float acc = 0.f;
      for (int e = 0; e < EMBN; ++e) acc = fmaf(Wenc[k*EMBN + e], W0[(size_t)e*1024 + j], acc);
      v = acc;
    } else {
      v = W0[(size_t)(k - 60)*1024 + j];  // 300 + (k-360)
    }
    if (VEC) wcat[(size_t)(k>>2)*4096 + (size_t)j*4 + (k&3)] = v;
    else     wcat[(size_t)k*1024 + j] = v;
  } else {
    float acc = 0.f;
    for (int e = 0; e < EMBN; ++e) acc = fmaf(benc[e], W0[(size_t)e*1024 + j], acc);
    b0[j] = acc;
  }
}

// ---- stage A: s0 from [x_t, h] @ Wcat; 4 rows/block ----------------------
template<bool VEC>
__global__ __launch_bounds__(256) void stage_a(
    const float* __restrict__ inputs, const float* __restrict__ wcat,
    const float* __restrict__ b0, const float* __restrict__ h,
    float* __restrict__ s0, int t)
{
  __shared__ float inp[4][KCAT + 32];
  const int tid = threadIdx.x;
  const int r0 = blockIdx.y * 4;
  for (int i = tid; i < 4*(INDN/4); i += 256) {
    int r = i / (INDN/4), c = i % (INDN/4);
    ((float4*)&inp[r][0])[c] =
      ((const float4*)(inputs + ((size_t)(r0+r)*TN + t)*INDN))[c];
  }
  for (int i = tid; i < 4*(HIDN/4); i += 256) {
    int r = i / (HIDN/4), c = i % (HIDN/4);
    *(float4*)&inp[r][INDN + c*4] = ((const float4*)(h + (size_t)(r0+r)*HIDN))[c];
  }
  __syncthreads();

  const int jl = tid & 63, rg = tid >> 6;
  const int j  = blockIdx.x*64 + jl;          // 0..511
  float c = 0.f, g = 0.f;
  if (VEC) {
    const float4* w4 = (const float4*)wcat;
    dot8<KCAT/4>(w4 + j, w4 + j + 512, &inp[rg][0], c, g);
  } else {
    dot_plain<KCAT/4>(wcat + j, &inp[rg][0], c, g);
  }
  c += b0[j]; g += b0[512 + j];
  float hv = inp[rg][INDN + j];
  s0[(size_t)(r0+rg)*HIDN + j] = hv + sigf(c)*(tanh_fast(g) - hv);
}

// ---- generic connection: s_out = inp + sig(c)*(act(g) - inp) -------------
template<bool VEC>
__global__ __launch_bounds__(256) void conn_k(ConnArgs args)
{
  ConnDesc d = args.d[blockIdx.z];
  __shared__ float inp[4][HIDN + 32];
  const int tid = threadIdx.x;
  const int r0 = blockIdx.y * 4;
  const float* src = d.in + (size_t)r0*HIDN;
  for (int i = tid; i < 4*HIDN/4; i += 256) {
    int r = i / (HIDN/4), c = i % (HIDN/4);
    *(float4*)&inp[r][c*4] = ((const float4*)src)[i];
  }
  __syncthreads();

  const int jl = tid & 63, rg = tid >> 6;
  const int j  = blockIdx.x*64 + jl;
  float c = 0.f, g = 0.f;
  if (VEC) {
    const float4* w4 = (const float4*)d.w;
    dot8<HIDN/4>(w4 + j, w4 + j + 512, &inp[rg][0], c, g);
  } else {
    dot_plain<HIDN/4>(d.w + j, &inp[rg][0], c, g);
  }
  float iv = inp[rg][j];
  d.out[(size_t)(r0+rg)*HIDN + j] = iv + sigf(c)*(actf(d.act, g) - iv);
}

// ---- stage E: s8 (relu conn on s5) + merge + output ----------------------
template<bool VEC>
__global__ __launch_bounds__(256) void stage_e(
    const float* __restrict__ s5, const float* __restrict__ w,
    const float* __restrict__ S, float* __restrict__ h,
    float* __restrict__ out, const float* __restrict__ masks, int t)
{
  __shared__ float inp[4][HIDN + 32];
  const int tid = threadIdx.x;
  const int r0 = blockIdx.y * 4;
  const float* src = s5 + (size_t)r0*HIDN;
  for (int i = tid; i < 4*HIDN/4; i += 256) {
    int r = i / (HIDN/4), c = i % (HIDN/4);
    *(float4*)&inp[r][c*4] = ((const float4*)src)[i];
  }
  __syncthreads();

  const int jl = tid & 63, rg = tid >> 6;
  const int j  = blockIdx.x*64 + jl;
  float c = 0.f, g = 0.f;
  if (VEC) {
    const float4* w4 = (const float4*)w;
    dot8<HIDN/4>(w4 + j, w4 + j + 512, &inp[rg][0], c, g);
  } else {
    dot_plain<HIDN/4>(w + j, &inp[rg][0], c, g);
  }
  const int r = r0 + rg;
  float iv = inp[rg][j];
  float s8 = iv + sigf(c)*(fmaxf(g, 0.f) - iv);
  float m = s8;
  #pragma unroll
  for (int i = 1; i <= 7; ++i) m += S[(size_t)i*(BN*HIDN) + (size_t)r*HIDN + j];
  m *= 0.125f;
  h[(size_t)r*HIDN + j] = m;
  out[((size_t)r*TN + t)*HIDN + j] = m * masks[(size_t)r*TN + t];
}

// ---- host-side step loop -------------------------------------------------
// ws layout (floats):
//   wcat : 0        size 958464  (872*1024 = 892928 used + slack for overrun)
//   b0   : 958464   size 1024
//   h    : 959488   size 65536
//   S    : 1025024  size 589824 (9 x 128*512)
//   wsT  : 1614848  size 8*524288 + 40960 slack   (VEC only)
template<bool VEC>
static void run_all(const float* inputs, const float* masks,
                    const float* Wenc, const float* benc,
                    const float* W0, const float* Wsp,
                    float* out, float* ws, hipStream_t stream)
{
  float* wcat = ws;
  float* b0   = ws + 958464;
  float* h    = ws + 959488;
  float* S    = ws + 1025024;
  float* wsT  = ws + 1614848;
  auto s = [&](int i){ return S + (size_t)i*(BN*HIDN); };
  auto W = [&](int i){ return (VEC ? wsT : Wsp) + (size_t)i*WSZ; };

  hipMemsetAsync(h, 0, (size_t)BN*HIDN*sizeof(float), stream);
  build_wcat<VEC><<<dim3(4, KCAT+1), 256, 0, stream>>>(Wenc, benc, W0, wcat, b0);
  if (VEC)
    transpose_ws<<<dim3(4, 128, 8), 256, 0, stream>>>(Wsp, wsT);

  const dim3 grid2(8, 32), blk(256);
  for (int t = 0; t < TN; ++t) {
    stage_a<VEC><<<grid2, blk, 0, stream>>>(inputs, wcat, b0, h, s(0), t);

    ConnArgs cb;  // s1 = tanh-conn(s0, W1); s4 = relu-conn(s0, W4)
    cb.d[0] = { s(0), s(1), W(0), 0 };
    cb.d[1] = { s(0), s(4), W(3), 1 };
    cb.d[2] = cb.d[0];
    conn_k<VEC><<<dim3(8,32,2), blk, 0, stream>>>(cb);

    ConnArgs cc;  // s2 = relu(s1,W2); s3 = tanh(s1,W3); s7 = tanh(s4,W7)
    cc.d[0] = { s(1), s(2), W(1), 1 };
    cc.d[1] = { s(1), s(3), W(2), 0 };
    cc.d[2] = { s(4), s(7), W(6), 0 };
    conn_k<VEC><<<dim3(8,32,3), blk, 0, stream>>>(cc);

    ConnArgs cd;  // s5 = id(s2,W5); s6 = sigm(s3,W6)
    cd.d[0] = { s(2), s(5), W(4), 2 };
    cd.d[1] = { s(3), s(6), W(5), 3 };
    cd.d[2] = cd.d[0];
    conn_k<VEC><<<dim3(8,32,2), blk, 0, stream>>>(cd);

    stage_e<VEC><<<grid2, blk, 0, stream>>>(s(5), W(7), S, h, out, masks, t);
  }
}

extern "C" void kernel_launch(void* const* d_in, const int* in_sizes, int n_in,
                              void* d_out, int out_size, void* d_ws, size_t ws_size,
                              hipStream_t stream)
{
  const float* inputs = (const float*)d_in[0];
  // d_in[1] = hidden: unused (reference starts from zeros)
  const float* masks  = (const float*)d_in[2];
  const float* Wenc   = (const float*)d_in[3];
  const float* benc   = (const float*)d_in[4];
  const float* W0     = (const float*)d_in[5];
  const float* Wsp    = (const float*)d_in[6];
  float* out = (float*)d_out;
  float* ws  = (float*)d_ws;

  const size_t need_vec = (size_t)(1614848 + 8*WSZ + 40960) * sizeof(float); // ~23.4 MB
  if (ws_size >= need_vec)
    run_all<true >(inputs, masks, Wenc, benc, W0, Wsp, out, ws, stream);
  else
    run_all<false>(inputs, masks, Wenc, benc, W0, Wsp, out, ws, stream);
}